// Round 8
// baseline (185.234 us; speedup 1.0000x reference)
//
#include <hip/hip_runtime.h>
#include <math.h>

#define NE 256
#define HD 4096
#define TOPKG 4
#define TOPK 8

#define BM 128
#define BK 32
#define NKB 128        // kb across full K
#define KS 2
#define KBS (NKB / KS) // 64

typedef __attribute__((ext_vector_type(8))) short short8;
typedef __attribute__((ext_vector_type(4))) float f32x4;

typedef __attribute__((address_space(1))) const void av1_void;
typedef __attribute__((address_space(3))) void av3_void;

__device__ __forceinline__ void g2l16(const void* g, void* l) {
  __builtin_amdgcn_global_load_lds((av1_void*)g, (av3_void*)l, 16, 0, 0);
}

#define MFMA __builtin_amdgcn_mfma_f32_16x16x32_bf16

// In-row XOR swizzle (involution): byte bits[5:4] ^= addr bits[8:7].
// Verified conflict-free (R3-R6: SQ_LDS_BANK_CONFLICT == 0).
__device__ __forceinline__ unsigned swz(unsigned a) {
  return a ^ (((a >> 7) & 3u) << 4);
}

// Round-to-nearest-even bf16 (inputs are finite, well-scaled).
__device__ __forceinline__ unsigned short rneb(float x) {
  unsigned u = __float_as_uint(x);
  return (unsigned short)((u + 0x7fffu + ((u >> 16) & 1u)) >> 16);
}
// 2-way ROUNDED split: x = h + m + rho, |rho| <~ 2^-18|x| (vs 2^-16 truncated).
__device__ __forceinline__ void split2(float x, unsigned short& h, unsigned short& m) {
  h = rneb(x);
  float r = x - __uint_as_float(((unsigned)h) << 16);  // exact (RN to lower precision)
  m = rneb(r);
}

// ---------------- W[e][k] -> packed rounded splits [kb][2][e 256][k 32] bf16 ----------------
__global__ void wsplit_kernel(const float* __restrict__ W, unsigned short* __restrict__ W2) {
  const int kb = blockIdx.x >> 1;
  const int e = (blockIdx.x & 1) * 128 + (threadIdx.x >> 1);
  const int seg = (threadIdx.x & 1) * 16;
  const float* src = W + (size_t)e * HD + kb * BK + seg;
  float4 x0 = *(const float4*)(src + 0);
  float4 x1 = *(const float4*)(src + 4);
  float4 x2 = *(const float4*)(src + 8);
  float4 x3 = *(const float4*)(src + 12);
  float xv[16] = {x0.x, x0.y, x0.z, x0.w, x1.x, x1.y, x1.z, x1.w,
                  x2.x, x2.y, x2.z, x2.w, x3.x, x3.y, x3.z, x3.w};
  short8 hv0, hv1, mv0, mv1;
#pragma unroll
  for (int j = 0; j < 8; ++j) {
    unsigned short h, m;
    split2(xv[j], h, m);
    hv0[j] = (short)h; mv0[j] = (short)m;
  }
#pragma unroll
  for (int j = 0; j < 8; ++j) {
    unsigned short h, m;
    split2(xv[8 + j], h, m);
    hv1[j] = (short)h; mv1[j] = (short)m;
  }
  unsigned short* dh = W2 + (size_t)kb * 16384 + (size_t)e * 32 + seg;  // h split
  unsigned short* dm = dh + 8192;                                       // m split
  *(short8*)(dh + 0) = hv0;
  *(short8*)(dh + 8) = hv1;
  *(short8*)(dm + 0) = mv0;
  *(short8*)(dm + 8) = mv1;
}

// ---------------- split-K logits: 128 tokens x 256 experts, K-window 2048 ----------------
// 512 thr = 8 waves (2m x 4n), wave tile 64x64. 4 chains {ah,am}x{bh,bm} share one
// fp32 acc (logit err ~4e-6). Full dbuf (A 16KB + B 32KB)*2 = 96KB -> m97 schedule:
// stage(kb+1 -> buf^1) BEFORE compute(buf), ONE barrier/kb (drain hidden by MFMA).
__global__ __launch_bounds__(512, 2) void logits_kernel(
    const float* __restrict__ X, const unsigned short* __restrict__ W2,
    float* __restrict__ Lp, int T) {
  __shared__ __align__(16) char lds[2 * 49152];  // per buf: Ah 8K | Am 8K | Bh 16K | Bm 16K

  const int tid = threadIdx.x;
  const int lane = tid & 63;
  const int wave = tid >> 6;
  const int wm = wave >> 2, wn = wave & 3;

  const int z = blockIdx.x >> 7;   // K-chunk
  const int y = blockIdx.x & 127;  // token block
  const int bm0 = y * BM;
  const int kb0 = z * KBS;

  // A staging: thread -> row tid>>2, 8-float segment tid&3
  const int arow = tid >> 2;
  const int aseg = tid & 3;
  const float* xptr = X + (size_t)(bm0 + arow) * HD + aseg * 8;
  const unsigned aw = swz((unsigned)(arow * 64 + aseg * 16));

  // fragment address components
  const int akg = lane >> 4;
  const int arf = wm * 64 + (lane & 15);
  const int bcf = wn * 64 + (lane & 15);

  f32x4 acc[4][4];
#pragma unroll
  for (int mi = 0; mi < 4; ++mi)
#pragma unroll
    for (int ni = 0; ni < 4; ++ni) acc[mi][ni] = (f32x4)(0.0f);

  const char* wbase = (const char*)W2;

  // B staging: 32KB slab, 4 rounds of 512thr x 16B; linear dest, pre-swizzled src.
  auto stageB = [&](int kbg, int ob) {
    const char* slab = wbase + (size_t)kbg * 32768;
#pragma unroll
    for (int r = 0; r < 4; ++r) {
      unsigned dl = (unsigned)(r * 8192 + tid * 16);
      g2l16(slab + swz(dl), &lds[ob + 16384 + dl]);
    }
  };

  auto convA = [&](int ob, const float* xv) {
    short8 hv, mv;
#pragma unroll
    for (int q = 0; q < 8; ++q) {
      unsigned short h, m;
      split2(xv[q], h, m);
      hv[q] = (short)h; mv[q] = (short)m;
    }
    *(short8*)(&lds[ob + aw]) = hv;
    *(short8*)(&lds[ob + 8192 + aw]) = mv;
  };

  // ---- prologue: stage kb0 into buf0 ----
  {
    const float* xp = xptr + (size_t)kb0 * BK;
    float4 xa = *(const float4*)(xp + 0);
    float4 xb = *(const float4*)(xp + 4);
    stageB(kb0, 0);
    float xv[8] = {xa.x, xa.y, xa.z, xa.w, xb.x, xb.y, xb.z, xb.w};
    convA(0, xv);
  }
  __syncthreads();

  for (int kb = 0; kb < KBS; ++kb) {
    const int bb = (kb & 1) * 49152;
    const int ob = bb ^ 49152;
    const bool more = (kb + 1 < KBS);

    float4 xa, xb;
    if (more) {
      // x loads FIRST, g2l16 AFTER: convA's vmcnt wait for x does not drain g2l16.
      const float* xp = xptr + (size_t)(kb0 + kb + 1) * BK;
      xa = *(const float4*)(xp + 0);
      xb = *(const float4*)(xp + 4);
      stageB(kb0 + kb + 1, ob);
    }

    // ---- frags from current buf: 8 A + 8 B ds_read_b128 ----
    short8 af[2][4], bf[2][4];
#pragma unroll
    for (int mi = 0; mi < 4; ++mi) {
      unsigned rb = swz((unsigned)((arf + mi * 16) * 64 + akg * 16));
      af[0][mi] = *(const short8*)(&lds[bb + rb]);
      af[1][mi] = *(const short8*)(&lds[bb + 8192 + rb]);
    }
#pragma unroll
    for (int ni = 0; ni < 4; ++ni) {
      unsigned cb = swz((unsigned)((bcf + ni * 16) * 64 + akg * 16));
      bf[0][ni] = *(const short8*)(&lds[bb + 16384 + cb]);
      bf[1][ni] = *(const short8*)(&lds[bb + 32768 + cb]);
    }

    __builtin_amdgcn_s_setprio(1);
    // term-major: 16 independent accs between dependent reuses
#pragma unroll
    for (int mi = 0; mi < 4; ++mi)
#pragma unroll
      for (int ni = 0; ni < 4; ++ni)
        acc[mi][ni] = MFMA(af[0][mi], bf[0][ni], acc[mi][ni], 0, 0, 0);
#pragma unroll
    for (int mi = 0; mi < 4; ++mi)
#pragma unroll
      for (int ni = 0; ni < 4; ++ni)
        acc[mi][ni] = MFMA(af[0][mi], bf[1][ni], acc[mi][ni], 0, 0, 0);
#pragma unroll
    for (int mi = 0; mi < 4; ++mi)
#pragma unroll
      for (int ni = 0; ni < 4; ++ni)
        acc[mi][ni] = MFMA(af[1][mi], bf[0][ni], acc[mi][ni], 0, 0, 0);
#pragma unroll
    for (int mi = 0; mi < 4; ++mi)
#pragma unroll
      for (int ni = 0; ni < 4; ++ni)
        acc[mi][ni] = MFMA(af[1][mi], bf[1][ni], acc[mi][ni], 0, 0, 0);
    __builtin_amdgcn_s_setprio(0);

    if (more) {
      float xv[8] = {xa.x, xa.y, xa.z, xa.w, xb.x, xb.y, xb.z, xb.w};
      convA(ob, xv);
    }
    __syncthreads();  // buf^1 fully staged (g2l16 landed under MFMA); buf free
  }

  // ---- epilogue: C/D col=lane&15, row=(lane>>4)*4+q ----
  float* outp = Lp + (size_t)z * ((size_t)T * NE);
#pragma unroll
  for (int mi = 0; mi < 4; ++mi)
#pragma unroll
    for (int ni = 0; ni < 4; ++ni) {
      int rowbase = bm0 + wm * 64 + mi * 16 + (lane >> 4) * 4;
      int col = wn * 64 + ni * 16 + (lane & 15);
#pragma unroll
      for (int q = 0; q < 4; ++q)
        outp[(size_t)(rowbase + q) * NE + col] = acc[mi][ni][q];
    }
}

// ---------------- gating: one wave per token, zero barriers (R6-proven) ----------------
__global__ __launch_bounds__(256) void topk_kernel(
    const float* __restrict__ Lp, const float* __restrict__ bias,
    float* __restrict__ out, int T, int ks) {
  const int lane = threadIdx.x & 63;
  const int t = blockIdx.x * 4 + (threadIdx.x >> 6);

  float4 bv = *(const float4*)(bias + lane * 4);
  double ba[4] = {bv.x, bv.y, bv.z, bv.w};

  double a0 = 0, a1 = 0, a2 = 0, a3 = 0;
  for (int zz = 0; zz < ks; ++zz) {
    float4 lv = *(const float4*)(Lp + (size_t)zz * T * NE + (size_t)t * NE + lane * 4);
    a0 += lv.x; a1 += lv.y; a2 += lv.z; a3 += lv.w;
  }
  double s[4] = {1.0 / (1.0 + exp(-a0)), 1.0 / (1.0 + exp(-a1)),
                 1.0 / (1.0 + exp(-a2)), 1.0 / (1.0 + exp(-a3))};
  double sc[4];
#pragma unroll
  for (int j = 0; j < 4; ++j) sc[j] = s[j] + ba[j];

  // group top-2 (group = 8 lanes = 32 experts)
  double m1 = sc[0], m2 = -1e300;
#pragma unroll
  for (int j = 1; j < 4; ++j) {
    if (sc[j] > m1) { m2 = m1; m1 = sc[j]; }
    else m2 = fmax(m2, sc[j]);
  }
#pragma unroll
  for (int off = 1; off <= 4; off <<= 1) {
    double o1 = __shfl_xor(m1, off);
    double o2 = __shfl_xor(m2, off);
    if (o1 > m1) { m2 = fmax(m1, o2); m1 = o1; }
    else m2 = fmax(m2, o1);
  }
  double gs = m1 + m2;

  double g[8];
#pragma unroll
  for (int gg = 0; gg < 8; ++gg) g[gg] = __shfl(gs, gg * 8);
  unsigned chosen = 0;
#pragma unroll
  for (int c = 0; c < TOPKG; ++c) {
    double best = -1e300; int bi = 0;
#pragma unroll
    for (int gg = 0; gg < 8; ++gg)
      if (!((chosen >> gg) & 1) && g[gg] > best) { best = g[gg]; bi = gg; }
    chosen |= 1u << bi;
  }
  const bool gsel = (chosen >> (lane >> 3)) & 1;

  double cand[4];
#pragma unroll
  for (int j = 0; j < 4; ++j) cand[j] = gsel ? sc[j] : -1e300;

  double wsel[TOPK]; int isel[TOPK];
  double denom = 1e-20;
#pragma unroll
  for (int it = 0; it < TOPK; ++it) {
    double v = cand[0]; int ji = 0;
#pragma unroll
    for (int j = 1; j < 4; ++j)
      if (cand[j] > v) { v = cand[j]; ji = j; }
    int idx = lane * 4 + ji;
#pragma unroll
    for (int off = 1; off <= 32; off <<= 1) {
      double ov = __shfl_xor(v, off);
      int oi = __shfl_xor(idx, off);
      if (ov > v || (ov == v && oi < idx)) { v = ov; idx = oi; }
    }
    int slot = idx & 3, owner = idx >> 2;
    double scand = s[0];
#pragma unroll
    for (int j = 1; j < 4; ++j) scand = (slot == j) ? s[j] : scand;
    double sval = __shfl(scand, owner);
    isel[it] = idx; wsel[it] = sval; denom += sval;
#pragma unroll
    for (int j = 0; j < 4; ++j)
      if (lane == owner && j == slot) cand[j] = -1e301;
  }

#pragma unroll
  for (int it = 0; it < TOPK; ++it)
    if (lane == it) {
      out[(size_t)t * TOPK + it] = (float)isel[it];
      out[(size_t)T * TOPK + (size_t)t * TOPK + it] =
          (float)(wsel[it] / denom * 2.5);
    }
}

extern "C" void kernel_launch(void* const* d_in, const int* in_sizes, int n_in,
                              void* d_out, int out_size, void* d_ws, size_t ws_size,
                              hipStream_t stream) {
  const float* X = (const float*)d_in[0];
  const float* W = (const float*)d_in[1];
  const float* bias = (const float*)d_in[2];
  float* out = (float*)d_out;
  int T = in_sizes[0] / HD;  // 16384

  unsigned short* W2 = (unsigned short*)d_ws;                 // 4 MB
  float* Lp = (float*)((char*)d_ws + (size_t)NKB * 32768);    // 2 x 16 MB partials

  wsplit_kernel<<<2 * NKB, 256, 0, stream>>>(W, W2);
  logits_kernel<<<128 * KS, 512, 0, stream>>>(X, W2, Lp, T);
  topk_kernel<<<T / 4, 256, 0, stream>>>(Lp, bias, out, T, KS);
}

// Round 9
// 163.888 us; speedup vs baseline: 1.1302x; 1.1302x over previous
//
#include <hip/hip_runtime.h>
#include <math.h>

#define NE 256
#define HD 4096
#define TOPKG 4
#define TOPK 8

#define BM 128
#define BK 32
#define NKB 128  // kb across full K

typedef __attribute__((ext_vector_type(8))) short short8;
typedef __attribute__((ext_vector_type(4))) float f32x4;

typedef __attribute__((address_space(1))) const void av1_void;
typedef __attribute__((address_space(3))) void av3_void;

__device__ __forceinline__ void g2l16(const void* g, void* l) {
  __builtin_amdgcn_global_load_lds((av1_void*)g, (av3_void*)l, 16, 0, 0);
}

#define MFMA __builtin_amdgcn_mfma_f32_16x16x32_bf16

// In-row XOR swizzle (involution): byte bits[5:4] ^= addr bits[8:7].
// Verified conflict-free (R3-R8: SQ_LDS_BANK_CONFLICT == 0).
__device__ __forceinline__ unsigned swz(unsigned a) {
  return a ^ (((a >> 7) & 3u) << 4);
}

// Round-to-nearest-even bf16.
__device__ __forceinline__ unsigned short rneb(float x) {
  unsigned u = __float_as_uint(x);
  return (unsigned short)((u + 0x7fffu + ((u >> 16) & 1u)) >> 16);
}
// 2-way ROUNDED split: x = h + m + rho, |rho| <~ 2^-18|x|. (R8-proven numerics.)
__device__ __forceinline__ void split2(float x, unsigned short& h, unsigned short& m) {
  h = rneb(x);
  float r = x - __uint_as_float(((unsigned)h) << 16);  // exact
  m = rneb(r);
}

// ---------------- W[e][k] -> packed rounded splits [kb][2][e 256][k 32] bf16 ----------------
__global__ void wsplit_kernel(const float* __restrict__ W, unsigned short* __restrict__ W2) {
  const int kb = blockIdx.x >> 1;
  const int e = (blockIdx.x & 1) * 128 + (threadIdx.x >> 1);
  const int seg = (threadIdx.x & 1) * 16;
  const float* src = W + (size_t)e * HD + kb * BK + seg;
  float4 x0 = *(const float4*)(src + 0);
  float4 x1 = *(const float4*)(src + 4);
  float4 x2 = *(const float4*)(src + 8);
  float4 x3 = *(const float4*)(src + 12);
  float xv[16] = {x0.x, x0.y, x0.z, x0.w, x1.x, x1.y, x1.z, x1.w,
                  x2.x, x2.y, x2.z, x2.w, x3.x, x3.y, x3.z, x3.w};
  short8 hv0, hv1, mv0, mv1;
#pragma unroll
  for (int j = 0; j < 8; ++j) {
    unsigned short h, m;
    split2(xv[j], h, m);
    hv0[j] = (short)h; mv0[j] = (short)m;
  }
#pragma unroll
  for (int j = 0; j < 8; ++j) {
    unsigned short h, m;
    split2(xv[8 + j], h, m);
    hv1[j] = (short)h; mv1[j] = (short)m;
  }
  unsigned short* dh = W2 + (size_t)kb * 16384 + (size_t)e * 32 + seg;  // h split
  unsigned short* dm = dh + 8192;                                       // m split
  *(short8*)(dh + 0) = hv0;
  *(short8*)(dh + 8) = hv1;
  *(short8*)(dm + 0) = mv0;
  *(short8*)(dm + 8) = mv1;
}

// ---------------- split-K logits: 128 tokens x 256 experts per block ----------------
// R6-proven structure: 256 thr = 4 waves (2m x 2n), wave tile 64x128, single-buffer
// A(16K)+B(32K) = 48KB -> 2 independent blocks/CU (phase-staggered overlap, m114).
// R8-proven math: 4 chains {ah,am}x{bh,bm}, one fp32 acc (err ~4e-6, fp64 z-sum in topk).
template <int KS>
__global__ __launch_bounds__(256, 2) void logits_kernel(
    const float* __restrict__ X, const unsigned short* __restrict__ W2,
    float* __restrict__ Lp, int T) {
  constexpr int KBS = NKB / KS;
  __shared__ __align__(16) char lds[49152];  // Ah 8K | Am 8K | Bh 16K | Bm 16K

  const int tid = threadIdx.x;
  const int lane = tid & 63;
  const int wave = tid >> 6;
  const int wm = wave >> 1, wn = wave & 1;

  // z-clustered XCD remap: contiguous d-range per XCD -> W2 slab L2-resident
  const int per_xcd = 16 * KS;
  const int d = (blockIdx.x & 7) * per_xcd + (blockIdx.x >> 3);
  const int z = d >> 7;
  const int y = d & 127;
  const int bm0 = y * BM;
  const int kb0 = z * KBS;

  // A staging: thread -> row tid>>1, 16-float half tid&1
  const int arow = tid >> 1;
  const int akh = tid & 1;
  const float* xptr = X + (size_t)(bm0 + arow) * HD + akh * 16;
  const unsigned aw0 = swz((unsigned)(arow * 64 + akh * 32));
  const unsigned aw1 = swz((unsigned)(arow * 64 + akh * 32 + 16));

  const int akg = lane >> 4;               // k-group (16B)
  const int arf = wm * 64 + (lane & 15);   // A row, + mi*16
  const int bcf = wn * 128 + (lane & 15);  // B col, + ni*16

  f32x4 acc[4][8];
#pragma unroll
  for (int mi = 0; mi < 4; ++mi)
#pragma unroll
    for (int ni = 0; ni < 8; ++ni) acc[mi][ni] = (f32x4)(0.0f);

  const char* wbase = (const char*)W2;

  // B staging: 32KB slab (h 16K | m 16K), 8 rounds of 256thr x 16B.
  // Linear dest, source pre-swizzled (involution).
  auto stageB = [&](int kbg) {
    const char* slab = wbase + (size_t)kbg * 32768;
#pragma unroll
    for (int r = 0; r < 8; ++r) {
      unsigned dl = (unsigned)(r * 4096 + tid * 16);
      g2l16(slab + swz(dl), &lds[16384 + dl]);
    }
  };

  auto convA = [&](const float* xv) {
    short8 hv0, hv1, mv0, mv1;
#pragma unroll
    for (int q = 0; q < 8; ++q) {
      unsigned short h, m;
      split2(xv[q], h, m);
      hv0[q] = (short)h; mv0[q] = (short)m;
    }
#pragma unroll
    for (int q = 0; q < 8; ++q) {
      unsigned short h, m;
      split2(xv[8 + q], h, m);
      hv1[q] = (short)h; mv1[q] = (short)m;
    }
    *(short8*)(&lds[aw0]) = hv0;
    *(short8*)(&lds[aw1]) = hv1;
    *(short8*)(&lds[8192 + aw0]) = mv0;
    *(short8*)(&lds[8192 + aw1]) = mv1;
  };

  // ---- prologue ----
  {
    const float* xp = xptr + (size_t)kb0 * BK;
    float4 x0 = *(const float4*)(xp + 0);
    float4 x1 = *(const float4*)(xp + 4);
    float4 x2 = *(const float4*)(xp + 8);
    float4 x3 = *(const float4*)(xp + 12);
    stageB(kb0);
    float xv[16] = {x0.x, x0.y, x0.z, x0.w, x1.x, x1.y, x1.z, x1.w,
                    x2.x, x2.y, x2.z, x2.w, x3.x, x3.y, x3.z, x3.w};
    convA(xv);
  }
  __syncthreads();

  for (int kb = 0; kb < KBS; ++kb) {
    const bool more = (kb + 1 < KBS);

    // A frags: 4 mi x 2 splits
    short8 af[2][4];
#pragma unroll
    for (int mi = 0; mi < 4; ++mi) {
      unsigned rb = swz((unsigned)((arf + mi * 16) * 64 + akg * 16));
      af[0][mi] = *(const short8*)(&lds[rb]);
      af[1][mi] = *(const short8*)(&lds[8192 + rb]);
    }

    // x prefetch for kb+1 (issued early; convA's vmcnt wait is FIFO-ordered
    // ahead of nothing else pending)
    float4 x0, x1, x2, x3;
    if (more) {
      const float* xp = xptr + (size_t)(kb0 + kb + 1) * BK;
      x0 = *(const float4*)(xp + 0);
      x1 = *(const float4*)(xp + 4);
      x2 = *(const float4*)(xp + 8);
      x3 = *(const float4*)(xp + 12);
    }

    __builtin_amdgcn_s_setprio(1);
#pragma unroll
    for (int ni = 0; ni < 8; ++ni) {
      unsigned cb = swz((unsigned)((bcf + ni * 16) * 64 + akg * 16));
      short8 bh = *(const short8*)(&lds[16384 + cb]);
      short8 bm_ = *(const short8*)(&lds[32768 + cb]);
      // 4 chains x 4 mi; term-major (independent accs between reuses)
#pragma unroll
      for (int mi = 0; mi < 4; ++mi) acc[mi][ni] = MFMA(af[0][mi], bh,  acc[mi][ni], 0, 0, 0);
#pragma unroll
      for (int mi = 0; mi < 4; ++mi) acc[mi][ni] = MFMA(af[0][mi], bm_, acc[mi][ni], 0, 0, 0);
#pragma unroll
      for (int mi = 0; mi < 4; ++mi) acc[mi][ni] = MFMA(af[1][mi], bh,  acc[mi][ni], 0, 0, 0);
#pragma unroll
      for (int mi = 0; mi < 4; ++mi) acc[mi][ni] = MFMA(af[1][mi], bm_, acc[mi][ni], 0, 0, 0);
    }
    __builtin_amdgcn_s_setprio(0);

    __syncthreads();  // all waves done reading LDS

    if (more) {
      stageB(kb0 + kb + 1);  // overwrite B (safe after barrier)
      float xv[16] = {x0.x, x0.y, x0.z, x0.w, x1.x, x1.y, x1.z, x1.w,
                      x2.x, x2.y, x2.z, x2.w, x3.x, x3.y, x3.z, x3.w};
      convA(xv);             // overwrite A; waits x only (FIFO vmcnt)
      __syncthreads();       // staging visible + g2l16 drained (block B covers stall)
    }
  }

  // ---- epilogue: C/D col=lane&15, row=(lane>>4)*4+q ----
  float* outp = Lp + (size_t)z * ((size_t)T * NE);
#pragma unroll
  for (int mi = 0; mi < 4; ++mi)
#pragma unroll
    for (int ni = 0; ni < 8; ++ni) {
      int rowbase = bm0 + wm * 64 + mi * 16 + (lane >> 4) * 4;
      int col = wn * 128 + ni * 16 + (lane & 15);
#pragma unroll
      for (int q = 0; q < 4; ++q)
        outp[(size_t)(rowbase + q) * NE + col] = acc[mi][ni][q];
    }
}

// ---------------- gating: one wave per token, zero barriers (R6-proven) ----------------
__global__ __launch_bounds__(256) void topk_kernel(
    const float* __restrict__ Lp, const float* __restrict__ bias,
    float* __restrict__ out, int T, int ks) {
  const int lane = threadIdx.x & 63;
  const int t = blockIdx.x * 4 + (threadIdx.x >> 6);

  float4 bv = *(const float4*)(bias + lane * 4);
  double ba[4] = {bv.x, bv.y, bv.z, bv.w};

  double a0 = 0, a1 = 0, a2 = 0, a3 = 0;
  for (int zz = 0; zz < ks; ++zz) {
    float4 lv = *(const float4*)(Lp + (size_t)zz * T * NE + (size_t)t * NE + lane * 4);
    a0 += lv.x; a1 += lv.y; a2 += lv.z; a3 += lv.w;
  }
  double s[4] = {1.0 / (1.0 + exp(-a0)), 1.0 / (1.0 + exp(-a1)),
                 1.0 / (1.0 + exp(-a2)), 1.0 / (1.0 + exp(-a3))};
  double sc[4];
#pragma unroll
  for (int j = 0; j < 4; ++j) sc[j] = s[j] + ba[j];

  // group top-2 (group = 8 lanes = 32 experts)
  double m1 = sc[0], m2 = -1e300;
#pragma unroll
  for (int j = 1; j < 4; ++j) {
    if (sc[j] > m1) { m2 = m1; m1 = sc[j]; }
    else m2 = fmax(m2, sc[j]);
  }
#pragma unroll
  for (int off = 1; off <= 4; off <<= 1) {
    double o1 = __shfl_xor(m1, off);
    double o2 = __shfl_xor(m2, off);
    if (o1 > m1) { m2 = fmax(m1, o2); m1 = o1; }
    else m2 = fmax(m2, o1);
  }
  double gs = m1 + m2;

  double g[8];
#pragma unroll
  for (int gg = 0; gg < 8; ++gg) g[gg] = __shfl(gs, gg * 8);
  unsigned chosen = 0;
#pragma unroll
  for (int c = 0; c < TOPKG; ++c) {
    double best = -1e300; int bi = 0;
#pragma unroll
    for (int gg = 0; gg < 8; ++gg)
      if (!((chosen >> gg) & 1) && g[gg] > best) { best = g[gg]; bi = gg; }
    chosen |= 1u << bi;
  }
  const bool gsel = (chosen >> (lane >> 3)) & 1;

  double cand[4];
#pragma unroll
  for (int j = 0; j < 4; ++j) cand[j] = gsel ? sc[j] : -1e300;

  double wsel[TOPK]; int isel[TOPK];
  double denom = 1e-20;
#pragma unroll
  for (int it = 0; it < TOPK; ++it) {
    double v = cand[0]; int ji = 0;
#pragma unroll
    for (int j = 1; j < 4; ++j)
      if (cand[j] > v) { v = cand[j]; ji = j; }
    int idx = lane * 4 + ji;
#pragma unroll
    for (int off = 1; off <= 32; off <<= 1) {
      double ov = __shfl_xor(v, off);
      int oi = __shfl_xor(idx, off);
      if (ov > v || (ov == v && oi < idx)) { v = ov; idx = oi; }
    }
    int slot = idx & 3, owner = idx >> 2;
    double scand = s[0];
#pragma unroll
    for (int j = 1; j < 4; ++j) scand = (slot == j) ? s[j] : scand;
    double sval = __shfl(scand, owner);
    isel[it] = idx; wsel[it] = sval; denom += sval;
#pragma unroll
    for (int j = 0; j < 4; ++j)
      if (lane == owner && j == slot) cand[j] = -1e301;
  }

#pragma unroll
  for (int it = 0; it < TOPK; ++it)
    if (lane == it) {
      out[(size_t)t * TOPK + it] = (float)isel[it];
      out[(size_t)T * TOPK + (size_t)t * TOPK + it] =
          (float)(wsel[it] / denom * 2.5);
    }
}

extern "C" void kernel_launch(void* const* d_in, const int* in_sizes, int n_in,
                              void* d_out, int out_size, void* d_ws, size_t ws_size,
                              hipStream_t stream) {
  const float* X = (const float*)d_in[0];
  const float* W = (const float*)d_in[1];
  const float* bias = (const float*)d_in[2];
  float* out = (float*)d_out;
  int T = in_sizes[0] / HD;  // 16384

  unsigned short* W2 = (unsigned short*)d_ws;               // 4 MB
  const size_t w2b = (size_t)NKB * 32768;
  float* Lp = (float*)((char*)d_ws + w2b);

  const size_t need4 = w2b + 4ull * T * NE * 4;             // 4 MB + 64 MB
  const int ks = (ws_size >= need4) ? 4 : 2;

  wsplit_kernel<<<2 * NKB, 256, 0, stream>>>(W, W2);
  if (ks == 4)
    logits_kernel<4><<<128 * 4, 256, 0, stream>>>(X, W2, Lp, T);
  else
    logits_kernel<2><<<128 * 2, 256, 0, stream>>>(X, W2, Lp, T);
  topk_kernel<<<T / 4, 256, 0, stream>>>(Lp, bias, out, T, ks);
}